// Round 2
// baseline (1007.717 us; speedup 1.0000x reference)
//
#include <hip/hip_runtime.h>
#include <hip/hip_bf16.h>

#define N_NODES 50000
#define N_EDGES 500000
constexpr int HID = 64;
constexpr int HC  = 256;   // HEADS*HID

typedef unsigned short u16;

__device__ __forceinline__ float b2f(u16 u) {
    union { unsigned int i; float f; } c; c.i = ((unsigned int)u) << 16; return c.f;
}
__device__ __forceinline__ u16 f2b(float f) {
    union { float f; unsigned int i; } c; c.f = f;
    unsigned int x = c.i;
    unsigned int lsb = (x >> 16) & 1u;
    x += 0x7fffu + lsb;
    return (u16)(x >> 16);
}
__device__ __forceinline__ float elu_f(float x) { return x > 0.f ? x : expm1f(x); }

// ---------------- edge_index layout detect (int32 vs int64) ----------------
// int64 layout: little-endian pairs (low,high); high words (odd 32-bit idx) all 0.
// int32 layout: odd words are src[1],src[3],... random node ids -> almost surely nonzero.
__global__ __launch_bounds__(256) void detect_kernel(const int* __restrict__ ei, int* __restrict__ flag) {
    int t = threadIdx.x;
    int v = ei[2 * t + 1];
    if (v != 0) atomicOr(flag, 1);   // 1 => int32 layout
}

// ---------------- CSR build (counting sort by dst) ----------------
__global__ __launch_bounds__(256) void hist_kernel(const int* __restrict__ ei, const int* __restrict__ flag,
                                                   int* __restrict__ cnt) {
    int e = blockIdx.x * 256 + threadIdx.x;
    if (e < N_EDGES) {
        int d = flag[0] ? ei[N_EDGES + e] : ei[2 * N_EDGES + 2 * e];
        atomicAdd(&cnt[d], 1);
    }
}

__global__ __launch_bounds__(1024) void scan_kernel(const int* __restrict__ cnt, int* __restrict__ row_start) {
    __shared__ int sc[1024];
    int t = threadIdx.x;
    const int C = (N_NODES + 1023) / 1024; // 49
    int s = t * C;
    int e = s + C < N_NODES ? s + C : N_NODES;
    int sum = 0;
    for (int i = s; i < e; ++i) sum += cnt[i];
    sc[t] = sum;
    __syncthreads();
    for (int off = 1; off < 1024; off <<= 1) {
        int v = (t >= off) ? sc[t - off] : 0;
        __syncthreads();
        sc[t] += v;
        __syncthreads();
    }
    int run = sc[t] - sum; // exclusive prefix
    for (int i = s; i < e; ++i) { row_start[i] = run; run += cnt[i]; }
    if (e == N_NODES && s < N_NODES) row_start[N_NODES] = run;
}

__global__ __launch_bounds__(256) void scatter_kernel(const int* __restrict__ ei, const int* __restrict__ flag,
                                const int* __restrict__ row_start, int* __restrict__ cursor,
                                int* __restrict__ csr_src) {
    int e = blockIdx.x * 256 + threadIdx.x;
    if (e < N_EDGES) {
        int isI32 = flag[0];
        int s = isI32 ? ei[e] : ei[2 * e];
        int d = isI32 ? ei[N_EDGES + e] : ei[2 * N_EDGES + 2 * e];
        int pos = row_start[d] + atomicAdd(&cursor[d], 1);
        csr_src[pos] = s;
    }
}

// ---------------- Encoder: 8->64 elu -> 64->64 elu ----------------
__global__ __launch_bounds__(256) void encoder_kernel(const float* __restrict__ x,
                               const float* __restrict__ w1, const float* __restrict__ b1,
                               const float* __restrict__ w2, const float* __restrict__ b2,
                               float* __restrict__ h) {
    __shared__ float w1s[64 * 9];
    __shared__ float w2s[64 * 65];
    __shared__ float b1s[64], b2s[64];
    __shared__ float t1s[4 * 65];
    int t = threadIdx.x;
    for (int i = t; i < 512; i += 256) { int r = i >> 3, c = i & 7; w1s[r * 9 + c] = w1[i]; }
    for (int i = t; i < 4096; i += 256) { int r = i >> 6, c = i & 63; w2s[r * 65 + c] = w2[i]; }
    if (t < 64) { b1s[t] = b1[t]; b2s[t] = b2[t]; }
    __syncthreads();
    int sub = t >> 6, j = t & 63;
    int base = blockIdx.x * 64;
    for (int g = 0; g < 16; ++g) {
        int n = base + g * 4 + sub;
        float acc = 0.f;
        if (n < N_NODES) {
            acc = b1s[j];
            #pragma unroll
            for (int m = 0; m < 8; ++m) acc += x[n * 8 + m] * w1s[j * 9 + m];
        }
        t1s[sub * 65 + j] = elu_f(acc);
        __syncthreads();
        float acc2 = b2s[j];
        #pragma unroll 8
        for (int k2 = 0; k2 < 64; ++k2) acc2 += t1s[sub * 65 + k2] * w2s[j * 65 + k2];
        if (n < N_NODES) h[n * 64 + j] = elu_f(acc2);
        __syncthreads();
    }
}

// ---------------- Projection GEMM: [q|k|v|skip] = h @ W^T + b ----------------
// grid.x: node tiles of 64, grid.y: 13 col tiles (0-3 q, 4-7 k, 8-11 v, 12 skip)
__global__ __launch_bounds__(256) void proj_kernel(const float* __restrict__ h,
    const float* __restrict__ Wq, const float* __restrict__ bq,
    const float* __restrict__ Wk, const float* __restrict__ bk,
    const float* __restrict__ Wv, const float* __restrict__ bv,
    const float* __restrict__ Wsk, const float* __restrict__ bsk,
    int layer,
    u16* __restrict__ q, u16* __restrict__ k, u16* __restrict__ v,
    float* __restrict__ skip)
{
    __shared__ float hs[64 * 68];
    __shared__ float wt[64 * 68];
    __shared__ float bias_s[64];
    int t = threadIdx.x;
    int m0 = blockIdx.x * 64;
    int ct = blockIdx.y;
    const float *Wp, *bp; u16* out16 = nullptr; float* outf = nullptr; int cbase;
    if (ct < 4)       { Wp = Wq  + layer * HC * HID;  bp = bq  + layer * HC;  out16 = q; cbase = ct * 64; }
    else if (ct < 8)  { Wp = Wk  + layer * HC * HID;  bp = bk  + layer * HC;  out16 = k; cbase = (ct - 4) * 64; }
    else if (ct < 12) { Wp = Wv  + layer * HC * HID;  bp = bv  + layer * HC;  out16 = v; cbase = (ct - 8) * 64; }
    else              { Wp = Wsk + layer * HID * HID; bp = bsk + layer * HID; outf = skip; cbase = 0; }

    #pragma unroll
    for (int r = 0; r < 4; ++r) {
        int p = t + r * 256; int m = p >> 4, kc = p & 15;
        int row = m0 + m;
        float4 val = make_float4(0.f, 0.f, 0.f, 0.f);
        if (row < N_NODES) val = *(const float4*)(h + row * 64 + kc * 4);
        *(float4*)&hs[m * 68 + kc * 4] = val;
    }
    #pragma unroll
    for (int r = 0; r < 4; ++r) {
        int p = t + r * 256; int j = p >> 4, kc = p & 15;
        float4 w4 = *(const float4*)(Wp + (cbase + j) * 64 + kc * 4);
        wt[(kc * 4 + 0) * 68 + j] = w4.x;
        wt[(kc * 4 + 1) * 68 + j] = w4.y;
        wt[(kc * 4 + 2) * 68 + j] = w4.z;
        wt[(kc * 4 + 3) * 68 + j] = w4.w;
    }
    if (t < 64) bias_s[t] = bp[cbase + t];
    __syncthreads();

    int tx = t & 15, ty = t >> 4;
    float acc[4][4] = {};
    #pragma unroll 8
    for (int kk = 0; kk < 64; ++kk) {
        float4 b4 = *(const float4*)&wt[kk * 68 + tx * 4];
        #pragma unroll
        for (int i = 0; i < 4; ++i) {
            float a = hs[(ty * 4 + i) * 68 + kk];
            acc[i][0] += a * b4.x; acc[i][1] += a * b4.y;
            acc[i][2] += a * b4.z; acc[i][3] += a * b4.w;
        }
    }
    #pragma unroll
    for (int i = 0; i < 4; ++i) {
        int row = m0 + ty * 4 + i;
        if (row >= N_NODES) continue;
        float o0 = acc[i][0] + bias_s[tx * 4 + 0];
        float o1 = acc[i][1] + bias_s[tx * 4 + 1];
        float o2 = acc[i][2] + bias_s[tx * 4 + 2];
        float o3 = acc[i][3] + bias_s[tx * 4 + 3];
        if (out16) {
            ushort4 o4; o4.x = f2b(o0); o4.y = f2b(o1); o4.z = f2b(o2); o4.w = f2b(o3);
            *(ushort4*)(out16 + row * 256 + cbase + tx * 4) = o4;
        } else {
            float4 o4 = make_float4(o0, o1, o2, o3);
            *(float4*)(outf + row * 64 + tx * 4) = o4;
        }
    }
}

// ---------------- Attention: one wave per dst node, CSR edge list ----------------
__global__ __launch_bounds__(256) void attn_kernel(
    const u16* __restrict__ q, const u16* __restrict__ k, const u16* __restrict__ v,
    const float* __restrict__ skip,
    const int* __restrict__ row_start, const int* __restrict__ csr_src,
    float* __restrict__ hout)
{
    int wave = threadIdx.x >> 6;
    int lane = threadIdx.x & 63;
    int n = blockIdx.x * 4 + wave;
    if (n >= N_NODES) return;
    int hh = lane >> 4, ii = lane & 15;
    const u16* qp = q + n * 256 + hh * 64 + ii;
    float q0 = b2f(qp[0]), q1 = b2f(qp[16]), q2 = b2f(qp[32]), q3 = b2f(qp[48]);
    float mx = -1e30f, l = 0.f;
    float a0 = 0.f, a1 = 0.f, a2 = 0.f, a3 = 0.f;
    int e0 = row_start[n], e1 = row_start[n + 1];
    for (int e = e0; e < e1; ++e) {
        int s = csr_src[e];
        const u16* kp = k + s * 256 + hh * 64 + ii;
        float part = q0 * b2f(kp[0]) + q1 * b2f(kp[16]) + q2 * b2f(kp[32]) + q3 * b2f(kp[48]);
        part += __shfl_xor(part, 1);
        part += __shfl_xor(part, 2);
        part += __shfl_xor(part, 4);
        part += __shfl_xor(part, 8);
        float alpha = part * 0.125f;
        float mn = fmaxf(mx, alpha);
        float sc = __expf(mx - mn);
        float p  = __expf(alpha - mn);
        l = l * sc + p;
        const u16* vp = v + s * 256 + hh * 64 + ii;
        a0 = a0 * sc + p * b2f(vp[0]);
        a1 = a1 * sc + p * b2f(vp[16]);
        a2 = a2 * sc + p * b2f(vp[32]);
        a3 = a3 * sc + p * b2f(vp[48]);
        mx = mn;
    }
    float inv = l > 0.f ? 1.f / l : 0.f;
    a0 *= inv; a1 *= inv; a2 *= inv; a3 *= inv;
    a0 += __shfl_xor(a0, 16); a0 += __shfl_xor(a0, 32);
    a1 += __shfl_xor(a1, 16); a1 += __shfl_xor(a1, 32);
    a2 += __shfl_xor(a2, 16); a2 += __shfl_xor(a2, 32);
    a3 += __shfl_xor(a3, 16); a3 += __shfl_xor(a3, 32);
    float sel = (hh == 0) ? a0 : (hh == 1) ? a1 : (hh == 2) ? a2 : a3;
    float o = 0.25f * sel + skip[n * 64 + lane];
    hout[n * 64 + lane] = elu_f(o);
}

// ---------------- Output MLP: 64->64 elu ->32 elu ->8 ----------------
__global__ __launch_bounds__(256) void mlp_kernel(const float* __restrict__ h,
    const float* __restrict__ w1, const float* __restrict__ b1,
    const float* __restrict__ w2, const float* __restrict__ b2,
    const float* __restrict__ w3, const float* __restrict__ b3,
    float* __restrict__ out)
{
    __shared__ float w1s[64 * 65];
    __shared__ float w2s[32 * 65];
    __shared__ float w3s[8 * 33];
    __shared__ float b1s[64], b2s[32], b3s[8];
    __shared__ float t1s[4 * 65];
    __shared__ float t2s[4 * 33];
    int t = threadIdx.x;
    for (int i = t; i < 4096; i += 256) { int r = i >> 6, c = i & 63; w1s[r * 65 + c] = w1[i]; }
    for (int i = t; i < 2048; i += 256) { int r = i >> 6, c = i & 63; w2s[r * 65 + c] = w2[i]; }
    if (t < 256) { int r = t >> 5, c = t & 31; w3s[r * 33 + c] = w3[t]; }
    if (t < 64) b1s[t] = b1[t];
    if (t < 32) b2s[t] = b2[t];
    if (t < 8)  b3s[t] = b3[t];
    __syncthreads();
    int sub = t >> 6, j = t & 63;
    int base = blockIdx.x * 64;
    for (int g = 0; g < 16; ++g) {
        int n = base + g * 4 + sub;
        float acc = b1s[j];
        if (n < N_NODES) {
            const float* hp = h + n * 64;
            #pragma unroll 8
            for (int k2 = 0; k2 < 64; ++k2) acc += hp[k2] * w1s[j * 65 + k2];
        }
        t1s[sub * 65 + j] = elu_f(acc);
        __syncthreads();
        if (j < 32) {
            float acc2 = b2s[j];
            #pragma unroll 8
            for (int k2 = 0; k2 < 64; ++k2) acc2 += t1s[sub * 65 + k2] * w2s[j * 65 + k2];
            t2s[sub * 33 + j] = elu_f(acc2);
        }
        __syncthreads();
        if (j < 8 && n < N_NODES) {
            float acc3 = b3s[j];
            #pragma unroll
            for (int k2 = 0; k2 < 32; ++k2) acc3 += t2s[sub * 33 + k2] * w3s[j * 33 + k2];
            out[n * 8 + j] = acc3;
        }
        __syncthreads();
    }
}

extern "C" void kernel_launch(void* const* d_in, const int* in_sizes, int n_in,
                              void* d_out, int out_size, void* d_ws, size_t ws_size,
                              hipStream_t stream) {
    (void)in_sizes; (void)n_in; (void)out_size; (void)ws_size;
    const float* x   = (const float*)d_in[0];
    const int* ei    = (const int*)d_in[1];
    const float* ew1 = (const float*)d_in[2];
    const float* eb1 = (const float*)d_in[3];
    const float* ew2 = (const float*)d_in[4];
    const float* eb2 = (const float*)d_in[5];
    const float* Wq  = (const float*)d_in[6];
    const float* bq  = (const float*)d_in[7];
    const float* Wk  = (const float*)d_in[8];
    const float* bk  = (const float*)d_in[9];
    const float* Wv  = (const float*)d_in[10];
    const float* bv  = (const float*)d_in[11];
    const float* Wsk = (const float*)d_in[12];
    const float* bsk = (const float*)d_in[13];
    const float* ow1 = (const float*)d_in[14];
    const float* ob1 = (const float*)d_in[15];
    const float* ow2 = (const float*)d_in[16];
    const float* ob2 = (const float*)d_in[17];
    const float* ow3 = (const float*)d_in[18];
    const float* ob3 = (const float*)d_in[19];

    char* ws = (char*)d_ws;
    size_t off = 0;
    auto alloc = [&](size_t bytes) -> void* {
        void* p = ws + off;
        off += (bytes + 255) & ~(size_t)255;
        return p;
    };
    float* h0    = (float*)alloc((size_t)N_NODES * 64 * 4);
    float* h1    = (float*)alloc((size_t)N_NODES * 64 * 4);
    u16*   q     = (u16*)  alloc((size_t)N_NODES * 256 * 2);
    u16*   k     = (u16*)  alloc((size_t)N_NODES * 256 * 2);
    u16*   v     = (u16*)  alloc((size_t)N_NODES * 256 * 2);
    float* skp   = (float*)alloc((size_t)N_NODES * 64 * 4);
    int*   cnt   = (int*)  alloc((size_t)N_NODES * 4);
    int*   cursor= (int*)  alloc((size_t)N_NODES * 4);
    int*   rowst = (int*)  alloc((size_t)(N_NODES + 1) * 4);
    int*   csr   = (int*)  alloc((size_t)N_EDGES * 4);
    int*   flag  = (int*)  alloc(256);

    hipMemsetAsync(cnt, 0, (size_t)N_NODES * 4, stream);
    hipMemsetAsync(cursor, 0, (size_t)N_NODES * 4, stream);
    hipMemsetAsync(flag, 0, 4, stream);

    detect_kernel<<<1, 256, 0, stream>>>(ei, flag);
    hist_kernel<<<(N_EDGES + 255) / 256, 256, 0, stream>>>(ei, flag, cnt);
    scan_kernel<<<1, 1024, 0, stream>>>(cnt, rowst);
    scatter_kernel<<<(N_EDGES + 255) / 256, 256, 0, stream>>>(ei, flag, rowst, cursor, csr);

    encoder_kernel<<<(N_NODES + 63) / 64, 256, 0, stream>>>(x, ew1, eb1, ew2, eb2, h0);

    float* hin = h0;
    float* hout = h1;
    for (int l = 0; l < 4; ++l) {
        dim3 g((N_NODES + 63) / 64, 13);
        proj_kernel<<<g, 256, 0, stream>>>(hin, Wq, bq, Wk, bk, Wv, bv, Wsk, bsk, l, q, k, v, skp);
        attn_kernel<<<(N_NODES + 3) / 4, 256, 0, stream>>>(q, k, v, skp, rowst, csr, hout);
        float* tmp = hin; hin = hout; hout = tmp;
    }

    mlp_kernel<<<(N_NODES + 63) / 64, 256, 0, stream>>>(hin, ow1, ob1, ow2, ob2, ow3, ob3, (float*)d_out);
}

// Round 3
// 814.387 us; speedup vs baseline: 1.2374x; 1.2374x over previous
//
#include <hip/hip_runtime.h>
#include <hip/hip_bf16.h>

#define N_NODES 50000
#define N_EDGES 500000
constexpr int HID = 64;
constexpr int HC  = 256;   // HEADS*HID

typedef unsigned short u16;
typedef __attribute__((ext_vector_type(8))) __bf16 bf16x8;
typedef __attribute__((ext_vector_type(4))) float f32x4;

__device__ __forceinline__ float b2f(u16 u) {
    union { unsigned int i; float f; } c; c.i = ((unsigned int)u) << 16; return c.f;
}
__device__ __forceinline__ u16 f2b(float f) {
    union { float f; unsigned int i; } c; c.f = f;
    unsigned int x = c.i;
    unsigned int lsb = (x >> 16) & 1u;
    x += 0x7fffu + lsb;
    return (u16)(x >> 16);
}
__device__ __forceinline__ float elu_f(float x) { return x > 0.f ? x : expm1f(x); }

// ---------------- edge_index layout detect (int32 vs int64) ----------------
__global__ __launch_bounds__(256) void detect_kernel(const int* __restrict__ ei, int* __restrict__ flag) {
    int t = threadIdx.x;
    int v = ei[2 * t + 1];
    if (v != 0) atomicOr(flag, 1);   // 1 => int32 layout
}

// ---------------- CSR build (counting sort by dst) ----------------
__global__ __launch_bounds__(256) void hist_kernel(const int* __restrict__ ei, const int* __restrict__ flag,
                                                   int* __restrict__ cnt) {
    int e = blockIdx.x * 256 + threadIdx.x;
    if (e < N_EDGES) {
        int d = flag[0] ? ei[N_EDGES + e] : ei[2 * N_EDGES + 2 * e];
        atomicAdd(&cnt[d], 1);
    }
}

__global__ __launch_bounds__(1024) void scan_kernel(const int* __restrict__ cnt, int* __restrict__ row_start) {
    __shared__ int sc[1024];
    int t = threadIdx.x;
    const int C = (N_NODES + 1023) / 1024; // 49
    int s = t * C;
    int e = s + C < N_NODES ? s + C : N_NODES;
    int sum = 0;
    for (int i = s; i < e; ++i) sum += cnt[i];
    sc[t] = sum;
    __syncthreads();
    for (int off = 1; off < 1024; off <<= 1) {
        int v = (t >= off) ? sc[t - off] : 0;
        __syncthreads();
        sc[t] += v;
        __syncthreads();
    }
    int run = sc[t] - sum; // exclusive prefix
    for (int i = s; i < e; ++i) { row_start[i] = run; run += cnt[i]; }
    if (e == N_NODES && s < N_NODES) row_start[N_NODES] = run;
}

__global__ __launch_bounds__(256) void scatter_kernel(const int* __restrict__ ei, const int* __restrict__ flag,
                                const int* __restrict__ row_start, int* __restrict__ cursor,
                                int* __restrict__ csr_src) {
    int e = blockIdx.x * 256 + threadIdx.x;
    if (e < N_EDGES) {
        int isI32 = flag[0];
        int s = isI32 ? ei[e] : ei[2 * e];
        int d = isI32 ? ei[N_EDGES + e] : ei[2 * N_EDGES + 2 * e];
        int pos = row_start[d] + atomicAdd(&cursor[d], 1);
        csr_src[pos] = s;
    }
}

// ---------------- Encoder: 8->64 elu -> 64->64 elu ----------------
__global__ __launch_bounds__(256) void encoder_kernel(const float* __restrict__ x,
                               const float* __restrict__ w1, const float* __restrict__ b1,
                               const float* __restrict__ w2, const float* __restrict__ b2,
                               float* __restrict__ h) {
    __shared__ float w1s[64 * 9];
    __shared__ float w2s[64 * 65];
    __shared__ float b1s[64], b2s[64];
    __shared__ float t1s[4 * 65];
    int t = threadIdx.x;
    for (int i = t; i < 512; i += 256) { int r = i >> 3, c = i & 7; w1s[r * 9 + c] = w1[i]; }
    for (int i = t; i < 4096; i += 256) { int r = i >> 6, c = i & 63; w2s[r * 65 + c] = w2[i]; }
    if (t < 64) { b1s[t] = b1[t]; b2s[t] = b2[t]; }
    __syncthreads();
    int sub = t >> 6, j = t & 63;
    int base = blockIdx.x * 64;
    for (int g = 0; g < 16; ++g) {
        int n = base + g * 4 + sub;
        float acc = 0.f;
        if (n < N_NODES) {
            acc = b1s[j];
            #pragma unroll
            for (int m = 0; m < 8; ++m) acc += x[n * 8 + m] * w1s[j * 9 + m];
        }
        t1s[sub * 65 + j] = elu_f(acc);
        __syncthreads();
        float acc2 = b2s[j];
        #pragma unroll 8
        for (int k2 = 0; k2 < 64; ++k2) acc2 += t1s[sub * 65 + k2] * w2s[j * 65 + k2];
        if (n < N_NODES) h[n * 64 + j] = elu_f(acc2);
        __syncthreads();
    }
}

// ---------------- Projection GEMM via bf16 MFMA ----------------
// [q|k|v|skip] = h @ W^T + b.  grid.x: 782 M-tiles of 64 rows,
// grid.y: 13 N-tiles of 64 cols (0-3 q, 4-7 k, 8-11 v, 12 skip).
// A frag / B frag: X[lane&15][(lane>>4)*8+j]  (W is stored N x K = B^T already)
// C/D: row=(lane>>4)*4+reg, col=lane&15   [guide-verified m89/m91]
__global__ __launch_bounds__(256) void proj_kernel(const float* __restrict__ h,
    const float* __restrict__ Wq, const float* __restrict__ bq,
    const float* __restrict__ Wk, const float* __restrict__ bk,
    const float* __restrict__ Wv, const float* __restrict__ bv,
    const float* __restrict__ Wsk, const float* __restrict__ bsk,
    int layer,
    u16* __restrict__ q, u16* __restrict__ k, u16* __restrict__ v,
    float* __restrict__ skip)
{
    __shared__ u16 as_tile[64 * 72];   // A: 64 rows x 64 k (bf16), pad to 72
    __shared__ u16 ws_tile[64 * 72];   // B^T: 64 cols x 64 k (bf16)
    __shared__ float bias_s[64];
    int t = threadIdx.x;
    int m0 = blockIdx.x * 64;
    int ct = blockIdx.y;
    const float *Wp, *bp; u16* out16 = nullptr; float* outf = nullptr; int cbase;
    if (ct < 4)       { Wp = Wq  + layer * HC * HID;  bp = bq  + layer * HC;  out16 = q; cbase = ct * 64; }
    else if (ct < 8)  { Wp = Wk  + layer * HC * HID;  bp = bk  + layer * HC;  out16 = k; cbase = (ct - 4) * 64; }
    else if (ct < 12) { Wp = Wv  + layer * HC * HID;  bp = bv  + layer * HC;  out16 = v; cbase = (ct - 8) * 64; }
    else              { Wp = Wsk + layer * HID * HID; bp = bsk + layer * HID; outf = skip; cbase = 0; }

    // stage A (h rows, fp32 -> bf16)
    #pragma unroll
    for (int r = 0; r < 4; ++r) {
        int p = t + r * 256; int row = p >> 4, kc = (p & 15) * 4;
        float4 val = make_float4(0.f, 0.f, 0.f, 0.f);
        if (m0 + row < N_NODES) val = *(const float4*)(h + (size_t)(m0 + row) * 64 + kc);
        ushort4 u; u.x = f2b(val.x); u.y = f2b(val.y); u.z = f2b(val.z); u.w = f2b(val.w);
        *(ushort4*)&as_tile[row * 72 + kc] = u;
    }
    // stage B (W rows, fp32 -> bf16); all 64 rows of every N-tile exist
    #pragma unroll
    for (int r = 0; r < 4; ++r) {
        int p = t + r * 256; int row = p >> 4, kc = (p & 15) * 4;
        float4 val = *(const float4*)(Wp + (size_t)(cbase + row) * 64 + kc);
        ushort4 u; u.x = f2b(val.x); u.y = f2b(val.y); u.z = f2b(val.z); u.w = f2b(val.w);
        *(ushort4*)&ws_tile[row * 72 + kc] = u;
    }
    if (t < 64) bias_s[t] = bp[cbase + t];
    __syncthreads();

    int wave = t >> 6, lane = t & 63;
    int lrow = lane & 15, quad = lane >> 4;
    int m_off = wave * 16;

    bf16x8 a0 = *(const bf16x8*)&as_tile[(m_off + lrow) * 72 + quad * 8];
    bf16x8 a1 = *(const bf16x8*)&as_tile[(m_off + lrow) * 72 + 32 + quad * 8];

    #pragma unroll
    for (int nsub = 0; nsub < 4; ++nsub) {
        bf16x8 b0 = *(const bf16x8*)&ws_tile[(nsub * 16 + lrow) * 72 + quad * 8];
        bf16x8 b1 = *(const bf16x8*)&ws_tile[(nsub * 16 + lrow) * 72 + 32 + quad * 8];
        f32x4 acc = {0.f, 0.f, 0.f, 0.f};
        acc = __builtin_amdgcn_mfma_f32_16x16x32_bf16(a0, b0, acc, 0, 0, 0);
        acc = __builtin_amdgcn_mfma_f32_16x16x32_bf16(a1, b1, acc, 0, 0, 0);
        int col = cbase + nsub * 16 + lrow;
        float bias = bias_s[nsub * 16 + lrow];
        #pragma unroll
        for (int r = 0; r < 4; ++r) {
            int row = m0 + m_off + quad * 4 + r;
            if (row < N_NODES) {
                float o = acc[r] + bias;
                if (out16) out16[(size_t)row * 256 + col] = f2b(o);
                else       outf[(size_t)row * 64 + col] = o;
            }
        }
    }
}

// ---------------- Attention: one wave per dst node, CSR edge list ----------------
// lane covers channels lane*4..lane*4+3 of the 256-wide q/k/v row:
// head = lane>>4, within-head elems (lane&15)*4+j  -> one ushort4 load per row.
__global__ __launch_bounds__(256) void attn_kernel(
    const u16* __restrict__ q, const u16* __restrict__ k, const u16* __restrict__ v,
    const float* __restrict__ skip,
    const int* __restrict__ row_start, const int* __restrict__ csr_src,
    float* __restrict__ hout)
{
    int wave = threadIdx.x >> 6;
    int lane = threadIdx.x & 63;
    int n = blockIdx.x * 4 + wave;
    if (n >= N_NODES) return;
    ushort4 q4 = ((const ushort4*)(q + (size_t)n * 256))[lane];
    float qf0 = b2f(q4.x), qf1 = b2f(q4.y), qf2 = b2f(q4.z), qf3 = b2f(q4.w);
    float mx = -1e30f, l = 0.f;
    float a0 = 0.f, a1 = 0.f, a2 = 0.f, a3 = 0.f;
    int e0 = row_start[n], e1 = row_start[n + 1];
    int e = e0;
    for (; e + 2 <= e1; e += 2) {
        int s0 = csr_src[e], s1 = csr_src[e + 1];
        ushort4 k40 = ((const ushort4*)(k + (size_t)s0 * 256))[lane];
        ushort4 k41 = ((const ushort4*)(k + (size_t)s1 * 256))[lane];
        ushort4 v40 = ((const ushort4*)(v + (size_t)s0 * 256))[lane];
        ushort4 v41 = ((const ushort4*)(v + (size_t)s1 * 256))[lane];
        float p0 = qf0 * b2f(k40.x) + qf1 * b2f(k40.y) + qf2 * b2f(k40.z) + qf3 * b2f(k40.w);
        float p1 = qf0 * b2f(k41.x) + qf1 * b2f(k41.y) + qf2 * b2f(k41.z) + qf3 * b2f(k41.w);
        p0 += __shfl_xor(p0, 1); p1 += __shfl_xor(p1, 1);
        p0 += __shfl_xor(p0, 2); p1 += __shfl_xor(p1, 2);
        p0 += __shfl_xor(p0, 4); p1 += __shfl_xor(p1, 4);
        p0 += __shfl_xor(p0, 8); p1 += __shfl_xor(p1, 8);
        float al0 = p0 * 0.125f, al1 = p1 * 0.125f;
        float mn = fmaxf(mx, fmaxf(al0, al1));
        float sc = __expf(mx - mn);
        float w0 = __expf(al0 - mn);
        float w1 = __expf(al1 - mn);
        l = l * sc + w0 + w1;
        a0 = a0 * sc + w0 * b2f(v40.x) + w1 * b2f(v41.x);
        a1 = a1 * sc + w0 * b2f(v40.y) + w1 * b2f(v41.y);
        a2 = a2 * sc + w0 * b2f(v40.z) + w1 * b2f(v41.z);
        a3 = a3 * sc + w0 * b2f(v40.w) + w1 * b2f(v41.w);
        mx = mn;
    }
    if (e < e1) {
        int s0 = csr_src[e];
        ushort4 k40 = ((const ushort4*)(k + (size_t)s0 * 256))[lane];
        ushort4 v40 = ((const ushort4*)(v + (size_t)s0 * 256))[lane];
        float p0 = qf0 * b2f(k40.x) + qf1 * b2f(k40.y) + qf2 * b2f(k40.z) + qf3 * b2f(k40.w);
        p0 += __shfl_xor(p0, 1);
        p0 += __shfl_xor(p0, 2);
        p0 += __shfl_xor(p0, 4);
        p0 += __shfl_xor(p0, 8);
        float al0 = p0 * 0.125f;
        float mn = fmaxf(mx, al0);
        float sc = __expf(mx - mn);
        float w0 = __expf(al0 - mn);
        l = l * sc + w0;
        a0 = a0 * sc + w0 * b2f(v40.x);
        a1 = a1 * sc + w0 * b2f(v40.y);
        a2 = a2 * sc + w0 * b2f(v40.z);
        a3 = a3 * sc + w0 * b2f(v40.w);
        mx = mn;
    }
    float inv = l > 0.f ? 1.f / l : 0.f;
    a0 *= inv; a1 *= inv; a2 *= inv; a3 *= inv;
    // sum over heads: lanes with equal (lane&15) hold heads 0..3
    a0 += __shfl_xor(a0, 16); a0 += __shfl_xor(a0, 32);
    a1 += __shfl_xor(a1, 16); a1 += __shfl_xor(a1, 32);
    a2 += __shfl_xor(a2, 16); a2 += __shfl_xor(a2, 32);
    a3 += __shfl_xor(a3, 16); a3 += __shfl_xor(a3, 32);
    if ((lane >> 4) == 0) {
        float4 sk = ((const float4*)(skip + (size_t)n * 64))[lane];
        float4 o;
        o.x = elu_f(0.25f * a0 + sk.x);
        o.y = elu_f(0.25f * a1 + sk.y);
        o.z = elu_f(0.25f * a2 + sk.z);
        o.w = elu_f(0.25f * a3 + sk.w);
        ((float4*)(hout + (size_t)n * 64))[lane] = o;
    }
}

// ---------------- Output MLP: 64->64 elu ->32 elu ->8 ----------------
__global__ __launch_bounds__(256) void mlp_kernel(const float* __restrict__ h,
    const float* __restrict__ w1, const float* __restrict__ b1,
    const float* __restrict__ w2, const float* __restrict__ b2,
    const float* __restrict__ w3, const float* __restrict__ b3,
    float* __restrict__ out)
{
    __shared__ float w1s[64 * 65];
    __shared__ float w2s[32 * 65];
    __shared__ float w3s[8 * 33];
    __shared__ float b1s[64], b2s[32], b3s[8];
    __shared__ float t1s[4 * 65];
    __shared__ float t2s[4 * 33];
    int t = threadIdx.x;
    for (int i = t; i < 4096; i += 256) { int r = i >> 6, c = i & 63; w1s[r * 65 + c] = w1[i]; }
    for (int i = t; i < 2048; i += 256) { int r = i >> 6, c = i & 63; w2s[r * 65 + c] = w2[i]; }
    if (t < 256) { int r = t >> 5, c = t & 31; w3s[r * 33 + c] = w3[t]; }
    if (t < 64) b1s[t] = b1[t];
    if (t < 32) b2s[t] = b2[t];
    if (t < 8)  b3s[t] = b3[t];
    __syncthreads();
    int sub = t >> 6, j = t & 63;
    int base = blockIdx.x * 64;
    for (int g = 0; g < 16; ++g) {
        int n = base + g * 4 + sub;
        float acc = b1s[j];
        if (n < N_NODES) {
            const float* hp = h + (size_t)n * 64;
            #pragma unroll 8
            for (int k2 = 0; k2 < 64; ++k2) acc += hp[k2] * w1s[j * 65 + k2];
        }
        t1s[sub * 65 + j] = elu_f(acc);
        __syncthreads();
        if (j < 32) {
            float acc2 = b2s[j];
            #pragma unroll 8
            for (int k2 = 0; k2 < 64; ++k2) acc2 += t1s[sub * 65 + k2] * w2s[j * 65 + k2];
            t2s[sub * 33 + j] = elu_f(acc2);
        }
        __syncthreads();
        if (j < 8 && n < N_NODES) {
            float acc3 = b3s[j];
            #pragma unroll
            for (int k2 = 0; k2 < 32; ++k2) acc3 += t2s[sub * 33 + k2] * w3s[j * 33 + k2];
            out[n * 8 + j] = acc3;
        }
        __syncthreads();
    }
}

extern "C" void kernel_launch(void* const* d_in, const int* in_sizes, int n_in,
                              void* d_out, int out_size, void* d_ws, size_t ws_size,
                              hipStream_t stream) {
    (void)in_sizes; (void)n_in; (void)out_size; (void)ws_size;
    const float* x   = (const float*)d_in[0];
    const int* ei    = (const int*)d_in[1];
    const float* ew1 = (const float*)d_in[2];
    const float* eb1 = (const float*)d_in[3];
    const float* ew2 = (const float*)d_in[4];
    const float* eb2 = (const float*)d_in[5];
    const float* Wq  = (const float*)d_in[6];
    const float* bq  = (const float*)d_in[7];
    const float* Wk  = (const float*)d_in[8];
    const float* bk  = (const float*)d_in[9];
    const float* Wv  = (const float*)d_in[10];
    const float* bv  = (const float*)d_in[11];
    const float* Wsk = (const float*)d_in[12];
    const float* bsk = (const float*)d_in[13];
    const float* ow1 = (const float*)d_in[14];
    const float* ob1 = (const float*)d_in[15];
    const float* ow2 = (const float*)d_in[16];
    const float* ob2 = (const float*)d_in[17];
    const float* ow3 = (const float*)d_in[18];
    const float* ob3 = (const float*)d_in[19];

    char* ws = (char*)d_ws;
    size_t off = 0;
    auto alloc = [&](size_t bytes) -> void* {
        void* p = ws + off;
        off += (bytes + 255) & ~(size_t)255;
        return p;
    };
    float* h0    = (float*)alloc((size_t)N_NODES * 64 * 4);
    float* h1    = (float*)alloc((size_t)N_NODES * 64 * 4);
    u16*   q     = (u16*)  alloc((size_t)N_NODES * 256 * 2);
    u16*   k     = (u16*)  alloc((size_t)N_NODES * 256 * 2);
    u16*   v     = (u16*)  alloc((size_t)N_NODES * 256 * 2);
    float* skp   = (float*)alloc((size_t)N_NODES * 64 * 4);
    int*   cnt   = (int*)  alloc((size_t)N_NODES * 4);
    int*   cursor= (int*)  alloc((size_t)N_NODES * 4);
    int*   rowst = (int*)  alloc((size_t)(N_NODES + 1) * 4);
    int*   csr   = (int*)  alloc((size_t)N_EDGES * 4);
    int*   flag  = (int*)  alloc(256);

    hipMemsetAsync(cnt, 0, (size_t)N_NODES * 4, stream);
    hipMemsetAsync(cursor, 0, (size_t)N_NODES * 4, stream);
    hipMemsetAsync(flag, 0, 4, stream);

    detect_kernel<<<1, 256, 0, stream>>>(ei, flag);
    hist_kernel<<<(N_EDGES + 255) / 256, 256, 0, stream>>>(ei, flag, cnt);
    scan_kernel<<<1, 1024, 0, stream>>>(cnt, rowst);
    scatter_kernel<<<(N_EDGES + 255) / 256, 256, 0, stream>>>(ei, flag, rowst, cursor, csr);

    encoder_kernel<<<(N_NODES + 63) / 64, 256, 0, stream>>>(x, ew1, eb1, ew2, eb2, h0);

    float* hin = h0;
    float* hout = h1;
    for (int l = 0; l < 4; ++l) {
        dim3 g((N_NODES + 63) / 64, 13);
        proj_kernel<<<g, 256, 0, stream>>>(hin, Wq, bq, Wk, bk, Wv, bv, Wsk, bsk, l, q, k, v, skp);
        attn_kernel<<<(N_NODES + 3) / 4, 256, 0, stream>>>(q, k, v, skp, rowst, csr, hout);
        float* tmp = hin; hin = hout; hout = tmp;
    }

    mlp_kernel<<<(N_NODES + 63) / 64, 256, 0, stream>>>(hin, ow1, ob1, ow2, ob2, ow3, ob3, (float*)d_out);
}

// Round 4
// 716.022 us; speedup vs baseline: 1.4074x; 1.1374x over previous
//
#include <hip/hip_runtime.h>
#include <hip/hip_bf16.h>

#define N_NODES 50000
#define N_EDGES 500000
constexpr int HID = 64;
constexpr int HC  = 256;   // HEADS*HID

typedef unsigned short u16;
typedef __attribute__((ext_vector_type(8))) __bf16 bf16x8;
typedef __attribute__((ext_vector_type(4))) float f32x4;

__device__ __forceinline__ float b2f(u16 u) {
    union { unsigned int i; float f; } c; c.i = ((unsigned int)u) << 16; return c.f;
}
__device__ __forceinline__ u16 f2b(float f) {
    union { float f; unsigned int i; } c; c.f = f;
    unsigned int x = c.i;
    unsigned int lsb = (x >> 16) & 1u;
    x += 0x7fffu + lsb;
    return (u16)(x >> 16);
}
__device__ __forceinline__ float elu_f(float x) { return x > 0.f ? x : expm1f(x); }

// ---------------- edge_index layout detect (int32 vs int64) ----------------
__global__ __launch_bounds__(256) void detect_kernel(const int* __restrict__ ei, int* __restrict__ flag) {
    int t = threadIdx.x;
    int v = ei[2 * t + 1];
    if (v != 0) atomicOr(flag, 1);   // 1 => int32 layout
}

// ---------------- CSR build (counting sort by dst) ----------------
__global__ __launch_bounds__(256) void hist_kernel(const int* __restrict__ ei, const int* __restrict__ flag,
                                                   int* __restrict__ cnt) {
    int e = blockIdx.x * 256 + threadIdx.x;
    if (e < N_EDGES) {
        int d = flag[0] ? ei[N_EDGES + e] : ei[2 * N_EDGES + 2 * e];
        atomicAdd(&cnt[d], 1);
    }
}

__global__ __launch_bounds__(1024) void scan_kernel(const int* __restrict__ cnt, int* __restrict__ row_start) {
    __shared__ int sc[1024];
    int t = threadIdx.x;
    const int C = (N_NODES + 1023) / 1024; // 49
    int s = t * C;
    int e = s + C < N_NODES ? s + C : N_NODES;
    int sum = 0;
    for (int i = s; i < e; ++i) sum += cnt[i];
    sc[t] = sum;
    __syncthreads();
    for (int off = 1; off < 1024; off <<= 1) {
        int v = (t >= off) ? sc[t - off] : 0;
        __syncthreads();
        sc[t] += v;
        __syncthreads();
    }
    int run = sc[t] - sum; // exclusive prefix
    for (int i = s; i < e; ++i) { row_start[i] = run; run += cnt[i]; }
    if (e == N_NODES && s < N_NODES) row_start[N_NODES] = run;
}

__global__ __launch_bounds__(256) void scatter_kernel(const int* __restrict__ ei, const int* __restrict__ flag,
                                const int* __restrict__ row_start, int* __restrict__ cursor,
                                int* __restrict__ csr_src) {
    int e = blockIdx.x * 256 + threadIdx.x;
    if (e < N_EDGES) {
        int isI32 = flag[0];
        int s = isI32 ? ei[e] : ei[2 * e];
        int d = isI32 ? ei[N_EDGES + e] : ei[2 * N_EDGES + 2 * e];
        int pos = row_start[d] + atomicAdd(&cursor[d], 1);
        csr_src[pos] = s;
    }
}

// ---------------- Encoder: 8->64 elu (VALU) -> 64->64 elu (MFMA) ----------------
// 64 nodes per block.
__global__ __launch_bounds__(256) void encoder_kernel(const float* __restrict__ x,
                               const float* __restrict__ w1, const float* __restrict__ b1,
                               const float* __restrict__ w2, const float* __restrict__ b2,
                               float* __restrict__ h) {
    __shared__ float xs[64 * 9];
    __shared__ float w1s[64 * 9];
    __shared__ u16 t1s[64 * 72];   // layer1 out, bf16, A-layout (row=node, k-contig)
    __shared__ u16 w2s[64 * 72];   // w2 as B^T (row=out col, k-contig), bf16
    __shared__ float b1s[64], b2s[64];
    int t = threadIdx.x;
    int m0 = blockIdx.x * 64;

    // stage x rows (64 x 8)
    if (t < 128) {
        int row = t >> 1, c = (t & 1) * 4;
        float4 val = make_float4(0.f, 0.f, 0.f, 0.f);
        if (m0 + row < N_NODES) val = *(const float4*)(x + (size_t)(m0 + row) * 8 + c);
        *(float4*)&xs[row * 9 + c] = val;
    }
    // stage w1 (64 x 8)
    if (t >= 128 && t < 256) {
        int p = t - 128;
        int row = p >> 1, c = (p & 1) * 4;
        float4 val = *(const float4*)(w1 + row * 8 + c);
        *(float4*)&w1s[row * 9 + c] = val;
    }
    // stage w2 as bf16 (64 x 64)
    #pragma unroll
    for (int r = 0; r < 4; ++r) {
        int p = t + r * 256; int row = p >> 4, kc = (p & 15) * 4;
        float4 val = *(const float4*)(w2 + row * 64 + kc);
        ushort4 u; u.x = f2b(val.x); u.y = f2b(val.y); u.z = f2b(val.z); u.w = f2b(val.w);
        *(ushort4*)&w2s[row * 72 + kc] = u;
    }
    if (t < 64) { b1s[t] = b1[t]; b2s[t] = b2[t]; }
    __syncthreads();

    // layer1: each thread computes 16 (node, j) outputs
    {
        int j = t & 63, sub = t >> 6;
        #pragma unroll
        for (int g = 0; g < 16; ++g) {
            int node = g * 4 + sub;
            float acc = b1s[j];
            #pragma unroll
            for (int m = 0; m < 8; ++m) acc += xs[node * 9 + m] * w1s[j * 9 + m];
            t1s[node * 72 + j] = f2b(elu_f(acc));
        }
    }
    __syncthreads();

    // layer2 via MFMA 16x16x32
    int wave = t >> 6, lane = t & 63;
    int lrow = lane & 15, quad = lane >> 4;
    int m_off = wave * 16;
    bf16x8 a0 = *(const bf16x8*)&t1s[(m_off + lrow) * 72 + quad * 8];
    bf16x8 a1 = *(const bf16x8*)&t1s[(m_off + lrow) * 72 + 32 + quad * 8];
    #pragma unroll
    for (int nsub = 0; nsub < 4; ++nsub) {
        bf16x8 b0 = *(const bf16x8*)&w2s[(nsub * 16 + lrow) * 72 + quad * 8];
        bf16x8 b1v = *(const bf16x8*)&w2s[(nsub * 16 + lrow) * 72 + 32 + quad * 8];
        f32x4 acc = {0.f, 0.f, 0.f, 0.f};
        acc = __builtin_amdgcn_mfma_f32_16x16x32_bf16(a0, b0, acc, 0, 0, 0);
        acc = __builtin_amdgcn_mfma_f32_16x16x32_bf16(a1, b1v, acc, 0, 0, 0);
        int col = nsub * 16 + lrow;
        float bias = b2s[col];
        #pragma unroll
        for (int r = 0; r < 4; ++r) {
            int row = m0 + m_off + quad * 4 + r;
            if (row < N_NODES) h[(size_t)row * 64 + col] = elu_f(acc[r] + bias);
        }
    }
}

// ---------------- Projection GEMM via bf16 MFMA ----------------
// [q|k|v|skip] = h @ W^T + b.  grid.x: 782 M-tiles of 64 rows,
// grid.y: 13 N-tiles of 64 cols (0-3 q, 4-7 k, 8-11 v, 12 skip).
__global__ __launch_bounds__(256) void proj_kernel(const float* __restrict__ h,
    const float* __restrict__ Wq, const float* __restrict__ bq,
    const float* __restrict__ Wk, const float* __restrict__ bk,
    const float* __restrict__ Wv, const float* __restrict__ bv,
    const float* __restrict__ Wsk, const float* __restrict__ bsk,
    int layer,
    u16* __restrict__ q, u16* __restrict__ k, u16* __restrict__ v,
    float* __restrict__ skip)
{
    __shared__ u16 as_tile[64 * 72];   // A: 64 rows x 64 k (bf16), pad to 72
    __shared__ u16 ws_tile[64 * 72];   // B^T: 64 cols x 64 k (bf16)
    __shared__ float bias_s[64];
    int t = threadIdx.x;
    int m0 = blockIdx.x * 64;
    int ct = blockIdx.y;
    const float *Wp, *bp; u16* out16 = nullptr; float* outf = nullptr; int cbase;
    if (ct < 4)       { Wp = Wq  + layer * HC * HID;  bp = bq  + layer * HC;  out16 = q; cbase = ct * 64; }
    else if (ct < 8)  { Wp = Wk  + layer * HC * HID;  bp = bk  + layer * HC;  out16 = k; cbase = (ct - 4) * 64; }
    else if (ct < 12) { Wp = Wv  + layer * HC * HID;  bp = bv  + layer * HC;  out16 = v; cbase = (ct - 8) * 64; }
    else              { Wp = Wsk + layer * HID * HID; bp = bsk + layer * HID; outf = skip; cbase = 0; }

    #pragma unroll
    for (int r = 0; r < 4; ++r) {
        int p = t + r * 256; int row = p >> 4, kc = (p & 15) * 4;
        float4 val = make_float4(0.f, 0.f, 0.f, 0.f);
        if (m0 + row < N_NODES) val = *(const float4*)(h + (size_t)(m0 + row) * 64 + kc);
        ushort4 u; u.x = f2b(val.x); u.y = f2b(val.y); u.z = f2b(val.z); u.w = f2b(val.w);
        *(ushort4*)&as_tile[row * 72 + kc] = u;
    }
    #pragma unroll
    for (int r = 0; r < 4; ++r) {
        int p = t + r * 256; int row = p >> 4, kc = (p & 15) * 4;
        float4 val = *(const float4*)(Wp + (size_t)(cbase + row) * 64 + kc);
        ushort4 u; u.x = f2b(val.x); u.y = f2b(val.y); u.z = f2b(val.z); u.w = f2b(val.w);
        *(ushort4*)&ws_tile[row * 72 + kc] = u;
    }
    if (t < 64) bias_s[t] = bp[cbase + t];
    __syncthreads();

    int wave = t >> 6, lane = t & 63;
    int lrow = lane & 15, quad = lane >> 4;
    int m_off = wave * 16;

    bf16x8 a0 = *(const bf16x8*)&as_tile[(m_off + lrow) * 72 + quad * 8];
    bf16x8 a1 = *(const bf16x8*)&as_tile[(m_off + lrow) * 72 + 32 + quad * 8];

    #pragma unroll
    for (int nsub = 0; nsub < 4; ++nsub) {
        bf16x8 b0 = *(const bf16x8*)&ws_tile[(nsub * 16 + lrow) * 72 + quad * 8];
        bf16x8 b1 = *(const bf16x8*)&ws_tile[(nsub * 16 + lrow) * 72 + 32 + quad * 8];
        f32x4 acc = {0.f, 0.f, 0.f, 0.f};
        acc = __builtin_amdgcn_mfma_f32_16x16x32_bf16(a0, b0, acc, 0, 0, 0);
        acc = __builtin_amdgcn_mfma_f32_16x16x32_bf16(a1, b1, acc, 0, 0, 0);
        int col = cbase + nsub * 16 + lrow;
        float bias = bias_s[nsub * 16 + lrow];
        #pragma unroll
        for (int r = 0; r < 4; ++r) {
            int row = m0 + m_off + quad * 4 + r;
            if (row < N_NODES) {
                float o = acc[r] + bias;
                if (out16) out16[(size_t)row * 256 + col] = f2b(o);
                else       outf[(size_t)row * 64 + col] = o;
            }
        }
    }
}

// ---------------- Attention: one wave per dst node, CSR edge list ----------------
__global__ __launch_bounds__(256) void attn_kernel(
    const u16* __restrict__ q, const u16* __restrict__ k, const u16* __restrict__ v,
    const float* __restrict__ skip,
    const int* __restrict__ row_start, const int* __restrict__ csr_src,
    float* __restrict__ hout)
{
    int wave = threadIdx.x >> 6;
    int lane = threadIdx.x & 63;
    int n = blockIdx.x * 4 + wave;
    if (n >= N_NODES) return;
    ushort4 q4 = ((const ushort4*)(q + (size_t)n * 256))[lane];
    float qf0 = b2f(q4.x), qf1 = b2f(q4.y), qf2 = b2f(q4.z), qf3 = b2f(q4.w);
    float mx = -1e30f, l = 0.f;
    float a0 = 0.f, a1 = 0.f, a2 = 0.f, a3 = 0.f;
    int e0 = row_start[n], e1 = row_start[n + 1];
    int e = e0;
    for (; e + 2 <= e1; e += 2) {
        int s0 = csr_src[e], s1 = csr_src[e + 1];
        ushort4 k40 = ((const ushort4*)(k + (size_t)s0 * 256))[lane];
        ushort4 k41 = ((const ushort4*)(k + (size_t)s1 * 256))[lane];
        ushort4 v40 = ((const ushort4*)(v + (size_t)s0 * 256))[lane];
        ushort4 v41 = ((const ushort4*)(v + (size_t)s1 * 256))[lane];
        float p0 = qf0 * b2f(k40.x) + qf1 * b2f(k40.y) + qf2 * b2f(k40.z) + qf3 * b2f(k40.w);
        float p1 = qf0 * b2f(k41.x) + qf1 * b2f(k41.y) + qf2 * b2f(k41.z) + qf3 * b2f(k41.w);
        p0 += __shfl_xor(p0, 1); p1 += __shfl_xor(p1, 1);
        p0 += __shfl_xor(p0, 2); p1 += __shfl_xor(p1, 2);
        p0 += __shfl_xor(p0, 4); p1 += __shfl_xor(p1, 4);
        p0 += __shfl_xor(p0, 8); p1 += __shfl_xor(p1, 8);
        float al0 = p0 * 0.125f, al1 = p1 * 0.125f;
        float mn = fmaxf(mx, fmaxf(al0, al1));
        float sc = __expf(mx - mn);
        float w0 = __expf(al0 - mn);
        float w1 = __expf(al1 - mn);
        l = l * sc + w0 + w1;
        a0 = a0 * sc + w0 * b2f(v40.x) + w1 * b2f(v41.x);
        a1 = a1 * sc + w0 * b2f(v40.y) + w1 * b2f(v41.y);
        a2 = a2 * sc + w0 * b2f(v40.z) + w1 * b2f(v41.z);
        a3 = a3 * sc + w0 * b2f(v40.w) + w1 * b2f(v41.w);
        mx = mn;
    }
    if (e < e1) {
        int s0 = csr_src[e];
        ushort4 k40 = ((const ushort4*)(k + (size_t)s0 * 256))[lane];
        ushort4 v40 = ((const ushort4*)(v + (size_t)s0 * 256))[lane];
        float p0 = qf0 * b2f(k40.x) + qf1 * b2f(k40.y) + qf2 * b2f(k40.z) + qf3 * b2f(k40.w);
        p0 += __shfl_xor(p0, 1);
        p0 += __shfl_xor(p0, 2);
        p0 += __shfl_xor(p0, 4);
        p0 += __shfl_xor(p0, 8);
        float al0 = p0 * 0.125f;
        float mn = fmaxf(mx, al0);
        float sc = __expf(mx - mn);
        float w0 = __expf(al0 - mn);
        l = l * sc + w0;
        a0 = a0 * sc + w0 * b2f(v40.x);
        a1 = a1 * sc + w0 * b2f(v40.y);
        a2 = a2 * sc + w0 * b2f(v40.z);
        a3 = a3 * sc + w0 * b2f(v40.w);
        mx = mn;
    }
    float inv = l > 0.f ? 1.f / l : 0.f;
    a0 *= inv; a1 *= inv; a2 *= inv; a3 *= inv;
    a0 += __shfl_xor(a0, 16); a0 += __shfl_xor(a0, 32);
    a1 += __shfl_xor(a1, 16); a1 += __shfl_xor(a1, 32);
    a2 += __shfl_xor(a2, 16); a2 += __shfl_xor(a2, 32);
    a3 += __shfl_xor(a3, 16); a3 += __shfl_xor(a3, 32);
    if ((lane >> 4) == 0) {
        float4 sk = ((const float4*)(skip + (size_t)n * 64))[lane];
        float4 o;
        o.x = elu_f(0.25f * a0 + sk.x);
        o.y = elu_f(0.25f * a1 + sk.y);
        o.z = elu_f(0.25f * a2 + sk.z);
        o.w = elu_f(0.25f * a3 + sk.w);
        ((float4*)(hout + (size_t)n * 64))[lane] = o;
    }
}

// ---------------- Output MLP: 64->64 elu (MFMA) ->32 elu (MFMA) ->8 (VALU) ----------------
// 64 nodes per block.
__global__ __launch_bounds__(256) void mlp_kernel(const float* __restrict__ h,
    const float* __restrict__ w1, const float* __restrict__ b1,
    const float* __restrict__ w2, const float* __restrict__ b2,
    const float* __restrict__ w3, const float* __restrict__ b3,
    float* __restrict__ out)
{
    __shared__ u16 hs[64 * 72];      // h tile bf16
    __shared__ u16 w1s[64 * 72];     // w1 B^T bf16
    __shared__ u16 t1s[64 * 72];     // layer1 out bf16
    __shared__ u16 w2s[32 * 72];     // w2 B^T bf16
    __shared__ float t2s[64 * 33];   // layer2 out fp32
    __shared__ float w3s[8 * 33];
    __shared__ float b1s[64], b2s[32], b3s[8];
    int t = threadIdx.x;
    int m0 = blockIdx.x * 64;

    #pragma unroll
    for (int r = 0; r < 4; ++r) {
        int p = t + r * 256; int row = p >> 4, kc = (p & 15) * 4;
        float4 val = make_float4(0.f, 0.f, 0.f, 0.f);
        if (m0 + row < N_NODES) val = *(const float4*)(h + (size_t)(m0 + row) * 64 + kc);
        ushort4 u; u.x = f2b(val.x); u.y = f2b(val.y); u.z = f2b(val.z); u.w = f2b(val.w);
        *(ushort4*)&hs[row * 72 + kc] = u;
    }
    #pragma unroll
    for (int r = 0; r < 4; ++r) {
        int p = t + r * 256; int row = p >> 4, kc = (p & 15) * 4;
        float4 val = *(const float4*)(w1 + row * 64 + kc);
        ushort4 u; u.x = f2b(val.x); u.y = f2b(val.y); u.z = f2b(val.z); u.w = f2b(val.w);
        *(ushort4*)&w1s[row * 72 + kc] = u;
    }
    #pragma unroll
    for (int r = 0; r < 2; ++r) {
        int p = t + r * 256; int row = p >> 4, kc = (p & 15) * 4;
        float4 val = *(const float4*)(w2 + row * 64 + kc);
        ushort4 u; u.x = f2b(val.x); u.y = f2b(val.y); u.z = f2b(val.z); u.w = f2b(val.w);
        *(ushort4*)&w2s[row * 72 + kc] = u;
    }
    if (t < 8 * 32) { int r = t >> 5, c = t & 31; w3s[r * 33 + c] = w3[t]; }
    if (t < 64) b1s[t] = b1[t];
    if (t >= 64 && t < 96) b2s[t - 64] = b2[t - 64];
    if (t >= 96 && t < 104) b3s[t - 96] = b3[t - 96];
    __syncthreads();

    int wave = t >> 6, lane = t & 63;
    int lrow = lane & 15, quad = lane >> 4;
    int m_off = wave * 16;

    // layer1 MFMA: 64 -> 64, elu, to bf16 LDS
    {
        bf16x8 a0 = *(const bf16x8*)&hs[(m_off + lrow) * 72 + quad * 8];
        bf16x8 a1 = *(const bf16x8*)&hs[(m_off + lrow) * 72 + 32 + quad * 8];
        #pragma unroll
        for (int nsub = 0; nsub < 4; ++nsub) {
            bf16x8 b0 = *(const bf16x8*)&w1s[(nsub * 16 + lrow) * 72 + quad * 8];
            bf16x8 b1v = *(const bf16x8*)&w1s[(nsub * 16 + lrow) * 72 + 32 + quad * 8];
            f32x4 acc = {0.f, 0.f, 0.f, 0.f};
            acc = __builtin_amdgcn_mfma_f32_16x16x32_bf16(a0, b0, acc, 0, 0, 0);
            acc = __builtin_amdgcn_mfma_f32_16x16x32_bf16(a1, b1v, acc, 0, 0, 0);
            int col = nsub * 16 + lrow;
            float bias = b1s[col];
            #pragma unroll
            for (int r = 0; r < 4; ++r) {
                int row = m_off + quad * 4 + r;
                t1s[row * 72 + col] = f2b(elu_f(acc[r] + bias));
            }
        }
    }
    __syncthreads();

    // layer2 MFMA: 64 -> 32, elu, to fp32 LDS
    {
        bf16x8 a0 = *(const bf16x8*)&t1s[(m_off + lrow) * 72 + quad * 8];
        bf16x8 a1 = *(const bf16x8*)&t1s[(m_off + lrow) * 72 + 32 + quad * 8];
        #pragma unroll
        for (int nsub = 0; nsub < 2; ++nsub) {
            bf16x8 b0 = *(const bf16x8*)&w2s[(nsub * 16 + lrow) * 72 + quad * 8];
            bf16x8 b1v = *(const bf16x8*)&w2s[(nsub * 16 + lrow) * 72 + 32 + quad * 8];
            f32x4 acc = {0.f, 0.f, 0.f, 0.f};
            acc = __builtin_amdgcn_mfma_f32_16x16x32_bf16(a0, b0, acc, 0, 0, 0);
            acc = __builtin_amdgcn_mfma_f32_16x16x32_bf16(a1, b1v, acc, 0, 0, 0);
            int col = nsub * 16 + lrow;
            float bias = b2s[col];
            #pragma unroll
            for (int r = 0; r < 4; ++r) {
                int row = m_off + quad * 4 + r;
                t2s[row * 33 + col] = elu_f(acc[r] + bias);
            }
        }
    }
    __syncthreads();

    // layer3 VALU: 32 -> 8, two outputs per thread, coalesced stores
    #pragma unroll
    for (int r = 0; r < 2; ++r) {
        int idx = t + r * 256;
        int node = idx >> 3, j = idx & 7;
        int row = m0 + node;
        if (row < N_NODES) {
            float acc = b3s[j];
            #pragma unroll
            for (int kk = 0; kk < 32; ++kk) acc += t2s[node * 33 + kk] * w3s[j * 33 + kk];
            out[(size_t)row * 8 + j] = acc;
        }
    }
}

extern "C" void kernel_launch(void* const* d_in, const int* in_sizes, int n_in,
                              void* d_out, int out_size, void* d_ws, size_t ws_size,
                              hipStream_t stream) {
    (void)in_sizes; (void)n_in; (void)out_size; (void)ws_size;
    const float* x   = (const float*)d_in[0];
    const int* ei    = (const int*)d_in[1];
    const float* ew1 = (const float*)d_in[2];
    const float* eb1 = (const float*)d_in[3];
    const float* ew2 = (const float*)d_in[4];
    const float* eb2 = (const float*)d_in[5];
    const float* Wq  = (const float*)d_in[6];
    const float* bq  = (const float*)d_in[7];
    const float* Wk  = (const float*)d_in[8];
    const float* bk  = (const float*)d_in[9];
    const float* Wv  = (const float*)d_in[10];
    const float* bv  = (const float*)d_in[11];
    const float* Wsk = (const float*)d_in[12];
    const float* bsk = (const float*)d_in[13];
    const float* ow1 = (const float*)d_in[14];
    const float* ob1 = (const float*)d_in[15];
    const float* ow2 = (const float*)d_in[16];
    const float* ob2 = (const float*)d_in[17];
    const float* ow3 = (const float*)d_in[18];
    const float* ob3 = (const float*)d_in[19];

    char* ws = (char*)d_ws;
    size_t off = 0;
    auto alloc = [&](size_t bytes) -> void* {
        void* p = ws + off;
        off += (bytes + 255) & ~(size_t)255;
        return p;
    };
    float* h0    = (float*)alloc((size_t)N_NODES * 64 * 4);
    float* h1    = (float*)alloc((size_t)N_NODES * 64 * 4);
    u16*   q     = (u16*)  alloc((size_t)N_NODES * 256 * 2);
    u16*   k     = (u16*)  alloc((size_t)N_NODES * 256 * 2);
    u16*   v     = (u16*)  alloc((size_t)N_NODES * 256 * 2);
    float* skp   = (float*)alloc((size_t)N_NODES * 64 * 4);
    int*   cnt   = (int*)  alloc((size_t)N_NODES * 4);
    int*   cursor= (int*)  alloc((size_t)N_NODES * 4);
    int*   rowst = (int*)  alloc((size_t)(N_NODES + 1) * 4);
    int*   csr   = (int*)  alloc((size_t)N_EDGES * 4);
    int*   flag  = (int*)  alloc(256);

    hipMemsetAsync(cnt, 0, (size_t)N_NODES * 4, stream);
    hipMemsetAsync(cursor, 0, (size_t)N_NODES * 4, stream);
    hipMemsetAsync(flag, 0, 4, stream);

    detect_kernel<<<1, 256, 0, stream>>>(ei, flag);
    hist_kernel<<<(N_EDGES + 255) / 256, 256, 0, stream>>>(ei, flag, cnt);
    scan_kernel<<<1, 1024, 0, stream>>>(cnt, rowst);
    scatter_kernel<<<(N_EDGES + 255) / 256, 256, 0, stream>>>(ei, flag, rowst, cursor, csr);

    encoder_kernel<<<(N_NODES + 63) / 64, 256, 0, stream>>>(x, ew1, eb1, ew2, eb2, h0);

    float* hin = h0;
    float* hout = h1;
    for (int l = 0; l < 4; ++l) {
        dim3 g((N_NODES + 63) / 64, 13);
        proj_kernel<<<g, 256, 0, stream>>>(hin, Wq, bq, Wk, bk, Wv, bv, Wsk, bsk, l, q, k, v, skp);
        attn_kernel<<<(N_NODES + 3) / 4, 256, 0, stream>>>(q, k, v, skp, rowst, csr, hout);
        float* tmp = hin; hin = hout; hout = tmp;
    }

    mlp_kernel<<<(N_NODES + 63) / 64, 256, 0, stream>>>(hin, ow1, ob1, ow2, ob2, ow3, ob3, (float*)d_out);
}